// Round 1
// baseline (853.661 us; speedup 1.0000x reference)
//
#include <hip/hip_runtime.h>

static constexpr int T_STEPS = 512;
static constexpr int NBATCH  = 256;
static constexpr int DD      = 128;                       // C = D = K = 128
static constexpr long TND    = (long)T_STEPS * NBATCH * DD; // 16777216 elems per output tensor

// ---------------------------------------------------------------------------
// Phase 1 / 3: O[M x 128] = A[M x 128] @ W^T + bias, W row-major (out,in).
// 64 rows x 128 cols per block, 128 threads, 8x8 register tile per thread.
// No LDS: A rows are lane-broadcast (read once from HBM), W is 64KB L1/L2-hot.
// ---------------------------------------------------------------------------
__global__ __launch_bounds__(128) void gemm128_bias(
    const float* __restrict__ A, const float* __restrict__ W,
    const float* __restrict__ bias, float* __restrict__ O) {
  const int tid = threadIdx.x;
  const int c   = tid & 15;          // d-group: d0 = 8*c covers 128 cols
  const int rg  = tid >> 4;          // row-group: r0 = 8*rg covers 64 rows
  const int d0  = c * 8;
  const long r0 = (long)blockIdx.x * 64 + rg * 8;

  float acc[8][8];
#pragma unroll
  for (int i = 0; i < 8; ++i)
#pragma unroll
    for (int j = 0; j < 8; ++j) acc[i][j] = 0.f;

  const float* Ab = A + r0 * DD;
  const float* Wb = W + (long)d0 * DD;

#pragma unroll 2
  for (int kq = 0; kq < 32; ++kq) {
    float4 xa[8], wa[8];
#pragma unroll
    for (int i = 0; i < 8; ++i) xa[i] = *(const float4*)(Ab + i * DD + kq * 4);
#pragma unroll
    for (int j = 0; j < 8; ++j) wa[j] = *(const float4*)(Wb + j * DD + kq * 4);
#pragma unroll
    for (int i = 0; i < 8; ++i)
#pragma unroll
      for (int j = 0; j < 8; ++j) {
        acc[i][j] += xa[i].x * wa[j].x;
        acc[i][j] += xa[i].y * wa[j].y;
        acc[i][j] += xa[i].z * wa[j].z;
        acc[i][j] += xa[i].w * wa[j].w;
      }
  }

  float bv[8];
#pragma unroll
  for (int j = 0; j < 8; ++j) bv[j] = bias[d0 + j];
#pragma unroll
  for (int i = 0; i < 8; ++i) {
    float4 o0, o1;
    o0.x = acc[i][0] + bv[0]; o0.y = acc[i][1] + bv[1];
    o0.z = acc[i][2] + bv[2]; o0.w = acc[i][3] + bv[3];
    o1.x = acc[i][4] + bv[4]; o1.y = acc[i][5] + bv[5];
    o1.z = acc[i][6] + bv[6]; o1.w = acc[i][7] + bv[7];
    *(float4*)(O + (r0 + i) * DD + d0)     = o0;
    *(float4*)(O + (r0 + i) * DD + d0 + 4) = o1;
  }
}

// ---------------------------------------------------------------------------
// Phase 2: sequential scan. One block per batch row n (rows are independent).
// 128 threads: lane = c*4 + jc; thread owns W_h rows d=4c..4c+3, cols
// j = 32*jc..32*jc+31 in 128 VGPRs (loaded once). h broadcast via 1KB LDS
// double buffer; per-step: 128 FMA/thread, shfl-xor reduce over 4 jc lanes,
// 1 barrier. xp[t] prefetched 2 steps ahead; h_t overwrites xp_t in-place.
// LDS padded +4 floats per 32 (pos(j)=j+4*(j>>5)) to break the jc*32 stride
// conflict (would be 4-way on every read otherwise).
// ---------------------------------------------------------------------------
__global__ __launch_bounds__(128) void rnn_scan(
    const float* __restrict__ Wh, float* __restrict__ H /* [T][N][128]; xp in, h out */) {
  const int tid = threadIdx.x;
  const int jc  = tid & 3;       // j-chunk 0..3 (32 j each)
  const int c   = tid >> 2;      // d-quad 0..31
  const int n   = blockIdx.x;

  // W_h slice -> registers (fully unrolled, constant indices)
  float w[4][32];
#pragma unroll
  for (int s = 0; s < 4; ++s) {
#pragma unroll
    for (int q = 0; q < 8; ++q) {
      float4 wv = *(const float4*)(Wh + (4 * c + s) * DD + jc * 32 + q * 4);
      w[s][q * 4 + 0] = wv.x; w[s][q * 4 + 1] = wv.y;
      w[s][q * 4 + 2] = wv.z; w[s][q * 4 + 3] = wv.w;
    }
  }

  __shared__ __align__(16) float hb[2][144];
  for (int i = tid; i < 2 * 144; i += 128) (&hb[0][0])[i] = 0.f;

  const long step = (long)NBATCH * DD;          // 32768 floats per timestep
  float* base = H + (long)n * DD + 4 * c;       // this lane's float4 slot (broadcast over jc)

  float4 xp0 = *(const float4*)(base);          // t = 0
  float4 xp1 = *(const float4*)(base + step);   // t = 1
  __syncthreads();

  int p = 0;
#pragma unroll 1
  for (int t = 0; t < T_STEPS; ++t) {
    const int tpre = (t + 2 < T_STEPS) ? (t + 2) : (T_STEPS - 1);
    float4 xpf = *(const float4*)(base + (long)tpre * step);   // prefetch

    float a0 = 0.f, a1 = 0.f, a2 = 0.f, a3 = 0.f;
#pragma unroll
    for (int q = 0; q < 8; ++q) {
      float4 h4 = *(const float4*)&hb[p][jc * 36 + q * 4];
      a0 += h4.x * w[0][q*4] + h4.y * w[0][q*4+1] + h4.z * w[0][q*4+2] + h4.w * w[0][q*4+3];
      a1 += h4.x * w[1][q*4] + h4.y * w[1][q*4+1] + h4.z * w[1][q*4+2] + h4.w * w[1][q*4+3];
      a2 += h4.x * w[2][q*4] + h4.y * w[2][q*4+1] + h4.z * w[2][q*4+2] + h4.w * w[2][q*4+3];
      a3 += h4.x * w[3][q*4] + h4.y * w[3][q*4+1] + h4.z * w[3][q*4+2] + h4.w * w[3][q*4+3];
    }
    // reduce partial-j sums over the 4 jc lanes (within a quad, within wave64)
    a0 += __shfl_xor(a0, 1); a0 += __shfl_xor(a0, 2);
    a1 += __shfl_xor(a1, 1); a1 += __shfl_xor(a1, 2);
    a2 += __shfl_xor(a2, 1); a2 += __shfl_xor(a2, 2);
    a3 += __shfl_xor(a3, 1); a3 += __shfl_xor(a3, 2);

    if (jc == 0) {
      float4 hv;
      hv.x = fmaxf(a0 + xp0.x, 0.f);
      hv.y = fmaxf(a1 + xp0.y, 0.f);
      hv.z = fmaxf(a2 + xp0.z, 0.f);
      hv.w = fmaxf(a3 + xp0.w, 0.f);
      const int pos = 4 * c + 4 * (c >> 3);           // pos(j)=j+4*(j>>5), j=4c
      *(float4*)&hb[p ^ 1][pos] = hv;                 // h for next step
      *(float4*)(base + (long)t * step) = hv;         // all_h output (overwrites consumed xp_t)
    }
    __syncthreads();
    p ^= 1;
    xp0 = xp1; xp1 = xpf;
  }
}

// ---------------------------------------------------------------------------
extern "C" void kernel_launch(void* const* d_in, const int* in_sizes, int n_in,
                              void* d_out, int out_size, void* d_ws, size_t ws_size,
                              hipStream_t stream) {
  const float* x  = (const float*)d_in[0];   // (T,N,C)
  const float* Wx = (const float*)d_in[1];   // (D,C)
  const float* bx = (const float*)d_in[2];   // (D)
  const float* Wh = (const float*)d_in[3];   // (D,D)
  const float* Wy = (const float*)d_in[4];   // (K,D)
  const float* by = (const float*)d_in[5];   // (K)

  float* Y = (float*)d_out;        // all_y: [T][N][K], first TND elems
  float* H = (float*)d_out + TND;  // all_h: [T][N][D], second TND elems

  const int M = T_STEPS * NBATCH;  // 131072 rows

  // Phase 1: xproj = x @ Wx^T + bx  -> staged into the all_h region
  gemm128_bias<<<M / 64, 128, 0, stream>>>(x, Wx, bx, H);
  // Phase 2: sequential scan, in-place xp -> h
  rnn_scan<<<NBATCH, 128, 0, stream>>>(Wh, H);
  // Phase 3: all_y = all_h @ Wy^T + by
  gemm128_bias<<<M / 64, 128, 0, stream>>>(H, Wy, by, Y);
}

// Round 2
// 561.415 us; speedup vs baseline: 1.5206x; 1.5206x over previous
//
#include <hip/hip_runtime.h>

static constexpr int T_STEPS = 512;
static constexpr int NBATCH  = 256;
static constexpr int DD      = 128;                         // C = D = K = 128
static constexpr long TND    = (long)T_STEPS * NBATCH * DD; // elems per output tensor

typedef short bf16x8 __attribute__((ext_vector_type(8)));   // 8 bf16 in 4 VGPRs
typedef float f32x4  __attribute__((ext_vector_type(4)));

__device__ inline unsigned short f2bf(float f) {            // RNE fp32 -> bf16
  unsigned u = __builtin_bit_cast(unsigned, f);
  unsigned r = u + 0x7FFFu + ((u >> 16) & 1u);
  return (unsigned short)(r >> 16);
}

__device__ inline bf16x8 pack8(const float* s) {
  bf16x8 v;
#pragma unroll
  for (int i = 0; i < 8; ++i) v[i] = (short)f2bf(s[i]);
  return v;
}

// ---------------------------------------------------------------------------
// Phase 1 / 3: O[M x 128] = A[M x 128] @ W^T + bias via bf16 MFMA, fp32 accum.
// One wave owns all of W as 32 register-resident B-fragments (128 VGPRs),
// then grid-strides over 16-row tiles: 8 A-loads + 32 MFMA + 32 stores/tile.
// Layouts (m89/m120-verified): A/B frag [lane&15][quad*8+j]; D col=lane&15,
// row=quad*4+reg.
// ---------------------------------------------------------------------------
__global__ __launch_bounds__(256) void gemm128_mfma(
    const float* __restrict__ A, const float* __restrict__ W,
    const float* __restrict__ bias, float* __restrict__ O, int ntiles) {
  const int lane = threadIdx.x & 63;
  const int wib  = threadIdx.x >> 6;     // wave in block (0..3)
  const int m    = lane & 15;            // row-in-tile / W-row-in-dtile
  const int q    = lane >> 4;            // quad: k-octet selector, C row group

  // B-frags: Wf[j][kq] = W[j*16+m][kq*32 + q*8 .. +7]  (all of W, bf16)
  bf16x8 Wf[8][4];
#pragma unroll
  for (int j = 0; j < 8; ++j)
#pragma unroll
    for (int kq = 0; kq < 4; ++kq) {
      const float* p = W + (j * 16 + m) * DD + kq * 32 + q * 8;
      float t[8];
      *(float4*)&t[0] = *(const float4*)p;
      *(float4*)&t[4] = *(const float4*)(p + 4);
      Wf[j][kq] = pack8(t);
    }
  float bv[8];
#pragma unroll
  for (int j = 0; j < 8; ++j) bv[j] = bias[j * 16 + m];

  const int wglobal = blockIdx.x * 4 + wib;
  const int nwaves  = gridDim.x * 4;
  for (int tile = wglobal; tile < ntiles; tile += nwaves) {
    const long r0 = (long)tile * 16;
    f32x4 acc[8];
#pragma unroll
    for (int j = 0; j < 8; ++j) acc[j] = (f32x4){0.f, 0.f, 0.f, 0.f};

#pragma unroll
    for (int kq = 0; kq < 4; ++kq) {
      const float* p = A + (r0 + m) * DD + kq * 32 + q * 8;
      float t[8];
      *(float4*)&t[0] = *(const float4*)p;
      *(float4*)&t[4] = *(const float4*)(p + 4);
      bf16x8 af = pack8(t);
#pragma unroll
      for (int j = 0; j < 8; ++j)
        acc[j] = __builtin_amdgcn_mfma_f32_16x16x32_bf16(af, Wf[j][kq], acc[j], 0, 0, 0);
    }
    // D[row=q*4+r][col=j*16+m] -> O, + bias
#pragma unroll
    for (int j = 0; j < 8; ++j)
#pragma unroll
      for (int r = 0; r < 4; ++r)
        O[(r0 + q * 4 + r) * DD + j * 16 + m] = acc[j][r] + bv[j];
  }
}

// ---------------------------------------------------------------------------
// Phase 2: sequential scan, one block (128 thr / 2 waves) per batch row.
// Same compute structure as R1, but global I/O is CHUNKED (8 steps): the
// __syncthreads() vmcnt(0) drain otherwise exposes full global latency every
// step. Now: 8 xp loads issued once per chunk, 8 h stores flushed once per
// chunk -> barrier drain paid 2x per 8 steps instead of 2x per step.
// ---------------------------------------------------------------------------
__global__ __launch_bounds__(128) void rnn_scan(
    const float* __restrict__ Wh, float* __restrict__ H /* [T][N][128] xp->h */) {
  const int tid = threadIdx.x;
  const int jc  = tid & 3;       // j-chunk 0..3 (32 j each)
  const int c   = tid >> 2;      // d-quad 0..31
  const int n   = blockIdx.x;

  float w[4][32];                // W_h slice in VGPRs
#pragma unroll
  for (int s = 0; s < 4; ++s)
#pragma unroll
    for (int qq = 0; qq < 8; ++qq) {
      float4 wv = *(const float4*)(Wh + (4 * c + s) * DD + jc * 32 + qq * 4);
      w[s][qq * 4 + 0] = wv.x; w[s][qq * 4 + 1] = wv.y;
      w[s][qq * 4 + 2] = wv.z; w[s][qq * 4 + 3] = wv.w;
    }

  __shared__ __align__(16) float hb[2][144];   // padded: pos(j)=j+4*(j>>5)
  for (int i = tid; i < 2 * 144; i += 128) (&hb[0][0])[i] = 0.f;

  const long step = (long)NBATCH * DD;
  float* base = H + (long)n * DD + 4 * c;      // lane's float4 slot (bcast over jc)

  float4 xpb[8], xpn[8];
#pragma unroll
  for (int i = 0; i < 8; ++i) xpb[i] = *(const float4*)(base + (long)i * step);
  __syncthreads();

  int p = 0;
#pragma unroll 1
  for (int ch = 0; ch < 64; ++ch) {
    const long tn0 = (ch < 63) ? (long)(ch + 1) * 8 : 63L * 8;  // clamp (unused on last)
#pragma unroll
    for (int i = 0; i < 8; ++i) xpn[i] = *(const float4*)(base + (tn0 + i) * step);

    float4 hsv[8];
#pragma unroll
    for (int ti = 0; ti < 8; ++ti) {
      float a0 = 0.f, a1 = 0.f, a2 = 0.f, a3 = 0.f;
#pragma unroll
      for (int qq = 0; qq < 8; ++qq) {
        float4 h4 = *(const float4*)&hb[p][jc * 36 + qq * 4];
        a0 += h4.x * w[0][qq*4] + h4.y * w[0][qq*4+1] + h4.z * w[0][qq*4+2] + h4.w * w[0][qq*4+3];
        a1 += h4.x * w[1][qq*4] + h4.y * w[1][qq*4+1] + h4.z * w[1][qq*4+2] + h4.w * w[1][qq*4+3];
        a2 += h4.x * w[2][qq*4] + h4.y * w[2][qq*4+1] + h4.z * w[2][qq*4+2] + h4.w * w[2][qq*4+3];
        a3 += h4.x * w[3][qq*4] + h4.y * w[3][qq*4+1] + h4.z * w[3][qq*4+2] + h4.w * w[3][qq*4+3];
      }
      a0 += __shfl_xor(a0, 1); a0 += __shfl_xor(a0, 2);
      a1 += __shfl_xor(a1, 1); a1 += __shfl_xor(a1, 2);
      a2 += __shfl_xor(a2, 1); a2 += __shfl_xor(a2, 2);
      a3 += __shfl_xor(a3, 1); a3 += __shfl_xor(a3, 2);

      if (jc == 0) {
        float4 hv;
        hv.x = fmaxf(a0 + xpb[ti].x, 0.f);
        hv.y = fmaxf(a1 + xpb[ti].y, 0.f);
        hv.z = fmaxf(a2 + xpb[ti].z, 0.f);
        hv.w = fmaxf(a3 + xpb[ti].w, 0.f);
        const int pos = 4 * c + 4 * (c >> 3);
        *(float4*)&hb[p ^ 1][pos] = hv;
        hsv[ti] = hv;
      }
      __syncthreads();
      p ^= 1;
    }

    if (jc == 0) {
#pragma unroll
      for (int ti = 0; ti < 8; ++ti)
        *(float4*)(base + (long)(ch * 8 + ti) * step) = hsv[ti];
    }
#pragma unroll
    for (int i = 0; i < 8; ++i) xpb[i] = xpn[i];
  }
}

// ---------------------------------------------------------------------------
extern "C" void kernel_launch(void* const* d_in, const int* in_sizes, int n_in,
                              void* d_out, int out_size, void* d_ws, size_t ws_size,
                              hipStream_t stream) {
  const float* x  = (const float*)d_in[0];   // (T,N,C)
  const float* Wx = (const float*)d_in[1];   // (D,C)
  const float* bx = (const float*)d_in[2];   // (D)
  const float* Wh = (const float*)d_in[3];   // (D,D)
  const float* Wy = (const float*)d_in[4];   // (K,D)
  const float* by = (const float*)d_in[5];   // (K)

  float* Y = (float*)d_out;        // all_y: [T][N][K]
  float* H = (float*)d_out + TND;  // all_h: [T][N][D]

  const int ntiles = T_STEPS * NBATCH / 16;  // 8192 row-tiles

  gemm128_mfma<<<512, 256, 0, stream>>>(x, Wx, bx, H, ntiles);   // xproj -> H
  rnn_scan<<<NBATCH, 128, 0, stream>>>(Wh, H);                   // in-place xp -> h
  gemm128_mfma<<<512, 256, 0, stream>>>(H, Wy, by, Y, ntiles);   // all_y
}